// Round 19
// baseline (406.553 us; speedup 1.0000x reference)
//
#include <hip/hip_runtime.h>
#include <hip/hip_cooperative_groups.h>

namespace cg = cooperative_groups;

#define TPB 1024
#define GRID 256   // coop capacity on this stack is <=256 blocks (r2/r7). Never exceed.

// r18 post-mortem: relaxed-poll fence = +5us; stall ~92us survives barrier
// count, packing, overlap, poll semantics -> the rendezvous structure itself.
// r19: per-wave atomic publication. Each wave: 5-level butterfly (masks 2..32)
// -> lanes 0/1 atomicAdd 4 cols/h into part[L][b][64] (fire-and-forget) ->
// release fence + cnt[L][b] += 1. Consumer polls ONE counter to 64. One
// __syncthreads per layer; no barrier2; no serial wave0 column-sum; red[][]
// LDS gone. Atomics are agent-scope = device-coherent (r1's "lost atomics"
// was actually a silent coop-launch no-op). part per-layer (7 slots), zeroed
// behind the existing replay-safety grid.sync.

typedef float f2 __attribute__((ext_vector_type(2)));
static __device__ __forceinline__ f2 spl(float s) { f2 r; r.x = s; r.y = s; return r; }

__global__ void risnet_kernel(
    const float* __restrict__ channel,
    const float* __restrict__ We1, const float* __restrict__ be1,
    const float* __restrict__ We,  const float* __restrict__ be,
    const float* __restrict__ Wo1, const float* __restrict__ bo1,
    const float* __restrict__ Wo,  const float* __restrict__ bo,
    const float* __restrict__ W8,  const float* __restrict__ b8,
    float* __restrict__ out, float* __restrict__ part, int* __restrict__ cnt)
{
  const int tid   = threadIdx.x;
  const int lane  = tid & 63;
  const int wv    = tid >> 6;                 // 0..15
  const int p     = tid & 1;                  // user-half: owns users 2p, 2p+1
  const int B     = blockIdx.x;
  const int b     = (B & 7) * 8 + ((B >> 3) & 7);  // same B%8 (XCD) per b-group (perf only)
  const int chunk = B >> 6;                   // 0..3
  const int n     = (chunk << 9) | (tid >> 1);// 0..2047

  __shared__ __align__(16) float biasE[2][16][4];  // [L&1][h][u] parity dbuf
  __shared__ __align__(16) float biasO[2][16][4];
  __shared__ float gv[64];                      // per-b means: ego-g 0..31, opp-g 32..63
  __shared__ float fin;

  // zero accumulators + counters (visible after the grid.sync below)
  {
    const int i = B * TPB + tid;
    if (i < 7*64*64)
      __hip_atomic_store(&part[i], 0.f, __ATOMIC_RELAXED, __HIP_MEMORY_SCOPE_AGENT);
    if (i < 7*64)
      __hip_atomic_store(&cnt[i], 0, __ATOMIC_RELAXED, __HIP_MEMORY_SCOPE_AGENT);
  }

  // per-thread channel slice, packed over the user pair: ch2[f] = {u=2p, u=2p+1}
  f2 ch2[4];
#pragma unroll
  for (int f = 0; f < 4; ++f) {
    ch2[f].x = channel[((b*4 + 2*p + 0)*4 + f)*2048 + n];
    ch2[f].y = channel[((b*4 + 2*p + 1)*4 + f)*2048 + n];
  }

  cg::grid_group grid = cg::this_grid();
  grid.sync();   // zeroing complete before any atomic accumulate (replay safety)

  f2 el2[8], ol2[8];

  // full parity-preserving wave reduce (masks 2..32; bit0 never flipped) then
  // lanes 0/1 publish 4 columns: lane0 -> u0,u1 ; lane1 -> u2,u3.
#define PUB5(Lb, base_col, a0, a1) { \
  a0 += __shfl_xor(a0, 2, 64);  a1 += __shfl_xor(a1, 2, 64);  \
  a0 += __shfl_xor(a0, 4, 64);  a1 += __shfl_xor(a1, 4, 64);  \
  a0 += __shfl_xor(a0, 8, 64);  a1 += __shfl_xor(a1, 8, 64);  \
  a0 += __shfl_xor(a0, 16, 64); a1 += __shfl_xor(a1, 16, 64); \
  a0 += __shfl_xor(a0, 32, 64); a1 += __shfl_xor(a1, 32, 64); \
  if (lane < 2) { \
    unsafeAtomicAdd(&part[(Lb) + (base_col) + 2*lane + 0], a0); \
    unsafeAtomicAdd(&part[(Lb) + (base_col) + 2*lane + 1], a1); \
  } }

  // this wave's contributions for layer idx are done (orders prior atomics)
#define DONE_CNT(idx) { \
  __builtin_amdgcn_fence(__ATOMIC_RELEASE, "agent"); \
  if (lane == 0) \
    __hip_atomic_fetch_add(&cnt[idx], 1, __ATOMIC_RELAXED, __HIP_MEMORY_SCOPE_AGENT); }

  // wait until all 64 waves (4 blocks x 16) published layer idx
#define SPIN_CNT(idx) { \
  for (;;) { \
    int c = __hip_atomic_load(&cnt[idx], __ATOMIC_RELAXED, __HIP_MEMORY_SCOPE_AGENT); \
    if (c >= 64) break; \
    __builtin_amdgcn_s_sleep(1); \
  } \
  __builtin_amdgcn_fence(__ATOMIC_ACQUIRE, "agent"); }

  // packed 20-col dot product (ch 0..3, el 4..11, ol 20..27), BINIT = bias or 0
#define DOT20B(ACC, W0, W1, W2, W5, W6, BINIT) { \
  f2 v = (BINIT); \
  v = spl(W0.x)*ch2[0] + v; v = spl(W0.y)*ch2[1] + v; \
  v = spl(W0.z)*ch2[2] + v; v = spl(W0.w)*ch2[3] + v; \
  v = spl(W1.x)*el2[0] + v; v = spl(W1.y)*el2[1] + v; \
  v = spl(W1.z)*el2[2] + v; v = spl(W1.w)*el2[3] + v; \
  v = spl(W2.x)*el2[4] + v; v = spl(W2.y)*el2[5] + v; \
  v = spl(W2.z)*el2[6] + v; v = spl(W2.w)*el2[7] + v; \
  v = spl(W5.x)*ol2[0] + v; v = spl(W5.y)*ol2[1] + v; \
  v = spl(W5.z)*ol2[2] + v; v = spl(W5.w)*ol2[3] + v; \
  v = spl(W6.x)*ol2[4] + v; v = spl(W6.y)*ol2[5] + v; \
  v = spl(W6.z)*ol2[6] + v; v = spl(W6.w)*ol2[7] + v; \
  ACC = v; }

  // ---------------- layer 0 (Cin = 4, bias static -> no exchange needed) ----
  {
    f2 opl2[8];
#pragma unroll
    for (int h = 0; h < 16; ++h) {
      const float4 w = *(const float4*)(We1 + h*4);
      f2 a = spl(be1[h]);
      a = spl(w.x)*ch2[0] + a; a = spl(w.y)*ch2[1] + a;
      a = spl(w.z)*ch2[2] + a; a = spl(w.w)*ch2[3] + a;
      a.x = fmaxf(a.x, 0.f); a.y = fmaxf(a.y, 0.f);
      if (h < 8) el2[h] = a;
      else { float a0 = a.x, a1 = a.y; PUB5(b*64, (h-8)*4, a0, a1) }
    }
#pragma unroll
    for (int h = 0; h < 16; ++h) {
      const float4 w = *(const float4*)(Wo1 + h*4);
      f2 a = spl(bo1[h]);
      a = spl(w.x)*ch2[0] + a; a = spl(w.y)*ch2[1] + a;
      a = spl(w.z)*ch2[2] + a; a = spl(w.w)*ch2[3] + a;
      a.x = fmaxf(a.x, 0.f); a.y = fmaxf(a.y, 0.f);
      if (h < 8) opl2[h] = a;
      else { float a0 = a.x, a1 = a.y; PUB5(b*64, 32 + (h-8)*4, a0, a1) }
    }
    DONE_CNT(b)
#pragma unroll
    for (int j = 0; j < 8; ++j) {
      const float s2 = opl2[j].x + opl2[j].y;
      const float s4 = s2 + __shfl_xor(s2, 1, 64);
      ol2[j] = (spl(s4) - opl2[j]) * spl(1.f/3.f);
    }
  }

  // ---------------- layers 1..6 (Cin = 36) ----------------
  for (int L = 1; L < 7; ++L) {
    const float* __restrict__ wEl = We + (L-1)*576;   // wave-uniform -> s_loads
    const float* __restrict__ wOl = Wo + (L-1)*576;
    const int bb = L & 1;          // bias parity buffer
    const int Lb = (L*64 + b)*64;  // this layer's accumulator row

    // --- phase 1: EGO conv, no bias (16 f2 cross the fold barrier) ---
    f2 accE2[16];
#pragma unroll
    for (int h = 0; h < 16; ++h) {
      const float4* wr = (const float4*)(wEl + h*36);
      const float4 w0 = wr[0], w1 = wr[1], w2 = wr[2], w5 = wr[5], w6 = wr[6];
      DOT20B(accE2[h], w0, w1, w2, w5, w6, spl(0.f))
    }

    // --- wave15: wait on counter, gather means, fold BOTH bias sets ---
    if (wv == 15) {
      SPIN_CNT((L-1)*64 + b)
      float s = __hip_atomic_load(&part[((L-1)*64 + b)*64 + lane],
                                  __ATOMIC_RELAXED, __HIP_MEMORY_SCOPE_AGENT);
      gv[lane] = s * (1.f/2048.f);
      // same-wave LDS RAW (r11-verified): lane owns (u,h), folds both convs
      const int u = lane & 3;
      const int h = lane >> 2;
      float bE = be[(L-1)*16 + h];
      float bO = bo[(L-1)*16 + h];
#pragma unroll
      for (int j = 0; j < 8; ++j) {
        const float eg = gv[j*4 + u];
        const float so = gv[32+j*4+0] + gv[32+j*4+1] + gv[32+j*4+2] + gv[32+j*4+3];
        const float og = (so - gv[32 + j*4 + u]) * (1.f/3.f);
        bE += wEl[h*36 + 12 + j] * eg + wEl[h*36 + 28 + j] * og;
        bO += wOl[h*36 + 12 + j] * eg + wOl[h*36 + 28 + j] * og;
      }
      biasE[bb][h][u] = bE;
      biasO[bb][h][u] = bO;
    }
    __syncthreads();   // the ONLY block-wide barrier this layer: biases ready

    // --- hi halves (stats-only) -> per-wave atomic publish, no rendezvous ---
#pragma unroll
    for (int h = 8; h < 16; ++h) {
      f2 a = accE2[h] + *(const f2*)&biasE[bb][h][2*p];
      float a0 = fmaxf(a.x, 0.f), a1 = fmaxf(a.y, 0.f);
      PUB5(Lb, (h-8)*4, a0, a1)
    }
#pragma unroll
    for (int h = 8; h < 16; ++h) {
      const float4* wr = (const float4*)(wOl + h*36);
      const float4 w0 = wr[0], w1 = wr[1], w2 = wr[2], w5 = wr[5], w6 = wr[6];
      f2 a;
      DOT20B(a, w0, w1, w2, w5, w6, *(const f2*)&biasO[bb][h][2*p])
      float a0 = fmaxf(a.x, 0.f), a1 = fmaxf(a.y, 0.f);
      PUB5(Lb, 32 + (h-8)*4, a0, a1)
    }
    DONE_CNT(L*64 + b)

    // --- lo halves in the propagation shadow ---
    f2 eln2[8];
#pragma unroll
    for (int h = 0; h < 8; ++h) {
      f2 a = accE2[h] + *(const f2*)&biasE[bb][h][2*p];
      a.x = fmaxf(a.x, 0.f); a.y = fmaxf(a.y, 0.f);
      eln2[h] = a;
    }
    f2 opl2[8];
#pragma unroll
    for (int h = 0; h < 8; ++h) {
      const float4* wr = (const float4*)(wOl + h*36);
      const float4 w0 = wr[0], w1 = wr[1], w2 = wr[2], w5 = wr[5], w6 = wr[6];
      f2 a;
      DOT20B(a, w0, w1, w2, w5, w6, *(const f2*)&biasO[bb][h][2*p])
      a.x = fmaxf(a.x, 0.f); a.y = fmaxf(a.y, 0.f);
      opl2[h] = a;
    }
#pragma unroll
    for (int j = 0; j < 8; ++j) {
      const float s2 = opl2[j].x + opl2[j].y;
      const float s4 = s2 + __shfl_xor(s2, 1, 64);
      ol2[j] = (spl(s4) - opl2[j]) * spl(1.f/3.f);
      el2[j] = eln2[j];
    }
  }

  // ---------------- final 1x1 conv + mean over users ----------------
  if (wv == 0) {
    SPIN_CNT(6*64 + b)
    float s = __hip_atomic_load(&part[(6*64 + b)*64 + lane],
                                __ATOMIC_RELAXED, __HIP_MEMORY_SCOPE_AGENT);
    gv[lane] = s * (1.f/2048.f);
    if (lane == 0) {
      float sf = b8[0];
#pragma unroll
      for (int j = 0; j < 8; ++j) {
        const float so = gv[32+j*4+0] + gv[32+j*4+1] + gv[32+j*4+2] + gv[32+j*4+3];
#pragma unroll
        for (int u = 0; u < 4; ++u) {
          const float eg = gv[j*4 + u];
          const float og = (so - gv[32 + j*4 + u]) * (1.f/3.f);
          sf += 0.25f * (W8[12 + j] * eg + W8[28 + j] * og);
        }
      }
      fin = sf;
    }
  }
  __syncthreads();
  f2 v = spl(0.f);
#pragma unroll
  for (int c = 0; c < 4; ++c) v = spl(W8[c]) * ch2[c] + v;
#pragma unroll
  for (int j = 0; j < 8; ++j) {
    v = spl(W8[4 + j]) * el2[j] + v;
    v = spl(W8[20 + j]) * ol2[j] + v;
  }
  float t = v.x + v.y;
  t += __shfl_xor(t, 1, 64);   // sum over all 4 users
  if (p == 0)
    out[b*2048 + n] = (fin + 0.25f * t) * 3.14159265358979f;
}

extern "C" void kernel_launch(void* const* d_in, const int* in_sizes, int n_in,
                              void* d_out, int out_size, void* d_ws, size_t ws_size,
                              hipStream_t stream) {
  const float* channel = (const float*)d_in[0];
  const float* We1 = (const float*)d_in[1];
  const float* be1 = (const float*)d_in[2];
  const float* We  = (const float*)d_in[3];
  const float* be  = (const float*)d_in[4];
  const float* Wo1 = (const float*)d_in[5];
  const float* bo1 = (const float*)d_in[6];
  const float* Wo  = (const float*)d_in[7];
  const float* bo  = (const float*)d_in[8];
  const float* W8  = (const float*)d_in[9];
  const float* b8  = (const float*)d_in[10];
  float* out  = (float*)d_out;
  float* part = (float*)d_ws;                       // 7*64*64 floats = 114688 B
  int*   cnt  = (int*)((char*)d_ws + 114688);       // 7*64 ints

  void* args[] = { (void*)&channel, (void*)&We1, (void*)&be1, (void*)&We, (void*)&be,
                   (void*)&Wo1, (void*)&bo1, (void*)&Wo, (void*)&bo,
                   (void*)&W8, (void*)&b8, (void*)&out, (void*)&part, (void*)&cnt };
  hipLaunchCooperativeKernel((void*)risnet_kernel, dim3(GRID), dim3(TPB), args, 0, stream);
}

// Round 20
// 132.937 us; speedup vs baseline: 3.0582x; 3.0582x over previous
//
#include <hip/hip_runtime.h>
#include <hip/hip_cooperative_groups.h>

namespace cg = cooperative_groups;

#define TPB 1024
#define GRID 256   // coop capacity on this stack is <=256 blocks (r2/r7). Never exceed.

// r19 post-mortem: per-wave agent RELEASE fences -> L2 writeback walk each
// (multi-XCD agent coherence point is past the XCD L2) -> 30MB writes, 406us.
// This also explains the invariant ~92us stall of r12-r18 (1 release store +
// 1 acquire fence per block per layer = serialized L2 cache-maintenance).
// r20 = r18 structure with a FENCE-FREE protocol: all cross-block data moves
// via agent-scope ATOMICS (coherence-point routed, correct on any XCD map);
// producer orders part-stores before flag-store with a raw s_waitcnt vmcnt(0)
// (pure drain, no cache ops); consumer polls relaxed + compiler barrier.

typedef float f2 __attribute__((ext_vector_type(2)));
static __device__ __forceinline__ f2 spl(float s) { f2 r; r.x = s; r.y = s; return r; }

__global__ void risnet_kernel(
    const float* __restrict__ channel,
    const float* __restrict__ We1, const float* __restrict__ be1,
    const float* __restrict__ We,  const float* __restrict__ be,
    const float* __restrict__ Wo1, const float* __restrict__ bo1,
    const float* __restrict__ Wo,  const float* __restrict__ bo,
    const float* __restrict__ W8,  const float* __restrict__ b8,
    float* __restrict__ out, float* __restrict__ part, int* __restrict__ flags)
{
  const int tid   = threadIdx.x;
  const int lane  = tid & 63;
  const int wv    = tid >> 6;                 // 0..15
  const int p     = tid & 1;                  // user-half: owns users 2p, 2p+1
  const int B     = blockIdx.x;
  const int b     = (B & 7) * 8 + ((B >> 3) & 7);  // same B%8 (XCD) per b-group (perf)
  const int chunk = B >> 6;                   // 0..3
  const int n     = (chunk << 9) | (tid >> 1);// 0..2047

  __shared__ __align__(16) float biasE[2][16][4];  // [L&1][h][u] parity dbuf
  __shared__ __align__(16) float biasO[2][16][4];
  __shared__ float red[64][64];                 // [row=wv*4+grp][conv*32+j*4+u]
  __shared__ float gv[64];                      // per-b means: ego-g 0..31, opp-g 32..63
  __shared__ float fin;

  if (tid == 0)
    __hip_atomic_store(&flags[B], 0, __ATOMIC_RELAXED, __HIP_MEMORY_SCOPE_AGENT);

  // per-thread channel slice, packed over the user pair: ch2[f] = {u=2p, u=2p+1}
  f2 ch2[4];
#pragma unroll
  for (int f = 0; f < 4; ++f) {
    ch2[f].x = channel[((b*4 + 2*p + 0)*4 + f)*2048 + n];
    ch2[f].y = channel[((b*4 + 2*p + 1)*4 + f)*2048 + n];
  }

  cg::grid_group grid = cg::this_grid();
  grid.sync();   // all flags zeroed before any block can set/wait (replay safety)

  f2 el2[8], ol2[8];

#define BFLY3(a0, a1) { \
  a0 += __shfl_xor(a0, 2, 64);  a1 += __shfl_xor(a1, 2, 64);  \
  a0 += __shfl_xor(a0, 4, 64);  a1 += __shfl_xor(a1, 4, 64);  \
  a0 += __shfl_xor(a0, 8, 64);  a1 += __shfl_xor(a1, 8, 64); }

#define RED_W(base_col, a0, a1) \
  if ((lane & 15) < 2) { \
    red[(wv<<2)|(lane>>4)][(base_col) + 2*(lane&1) + 0] = a0; \
    red[(wv<<2)|(lane>>4)][(base_col) + 2*(lane&1) + 1] = a1; }

// publish: wave0 sums red columns, atomically stores part (agent scope ->
// coherence-point write, no cache walk), drains vmcnt, then stores the flag.
// NO release fence anywhere.
#define PUBLISH(Lpar, Lval) { \
  __syncthreads(); \
  if (tid < 64) { \
    float s0 = 0.f, s1 = 0.f, s2 = 0.f, s3 = 0.f; \
    _Pragma("unroll") for (int r = 0; r < 64; r += 4) { \
      s0 += red[r+0][tid]; s1 += red[r+1][tid]; \
      s2 += red[r+2][tid]; s3 += red[r+3][tid]; \
    } \
    __hip_atomic_store(&part[(((Lpar)*64 + b)*4 + chunk)*64 + tid], \
                       (s0+s1)+(s2+s3), \
                       __ATOMIC_RELAXED, __HIP_MEMORY_SCOPE_AGENT); \
    asm volatile("s_waitcnt vmcnt(0)" ::: "memory"); \
    if (lane == 0) \
      __hip_atomic_store(&flags[B], (Lval), __ATOMIC_RELAXED, __HIP_MEMORY_SCOPE_AGENT); \
  } }

  // relaxed spin; compiler-only barrier after (part loads are atomic reads
  // issued after the poll breaks -> read the coherence point, no inv walk)
#define SPIN_RELAXED(tgt) { \
  const int gi = (B & 63) | ((lane & 3) << 6); \
  for (;;) { \
    int f = __hip_atomic_load(&flags[gi], __ATOMIC_RELAXED, __HIP_MEMORY_SCOPE_AGENT); \
    if (__all(f >= (tgt))) break; \
    __builtin_amdgcn_s_sleep(1); \
  } \
  asm volatile("" ::: "memory"); }

  // packed 20-col dot product (ch 0..3, el 4..11, ol 20..27), BINIT = bias or 0
#define DOT20B(ACC, W0, W1, W2, W5, W6, BINIT) { \
  f2 v = (BINIT); \
  v = spl(W0.x)*ch2[0] + v; v = spl(W0.y)*ch2[1] + v; \
  v = spl(W0.z)*ch2[2] + v; v = spl(W0.w)*ch2[3] + v; \
  v = spl(W1.x)*el2[0] + v; v = spl(W1.y)*el2[1] + v; \
  v = spl(W1.z)*el2[2] + v; v = spl(W1.w)*el2[3] + v; \
  v = spl(W2.x)*el2[4] + v; v = spl(W2.y)*el2[5] + v; \
  v = spl(W2.z)*el2[6] + v; v = spl(W2.w)*el2[7] + v; \
  v = spl(W5.x)*ol2[0] + v; v = spl(W5.y)*ol2[1] + v; \
  v = spl(W5.z)*ol2[2] + v; v = spl(W5.w)*ol2[3] + v; \
  v = spl(W6.x)*ol2[4] + v; v = spl(W6.y)*ol2[5] + v; \
  v = spl(W6.z)*ol2[6] + v; v = spl(W6.w)*ol2[7] + v; \
  ACC = v; }

  // ---------------- layer 0 (Cin = 4, feats = ch) ----------------
  {
    f2 opl2[8];
#pragma unroll
    for (int h = 0; h < 16; ++h) {
      const float4 w = *(const float4*)(We1 + h*4);
      f2 a = spl(be1[h]);
      a = spl(w.x)*ch2[0] + a; a = spl(w.y)*ch2[1] + a;
      a = spl(w.z)*ch2[2] + a; a = spl(w.w)*ch2[3] + a;
      a.x = fmaxf(a.x, 0.f); a.y = fmaxf(a.y, 0.f);
      if (h < 8) el2[h] = a;
      else { float a0 = a.x, a1 = a.y; BFLY3(a0, a1); RED_W((h-8)*4, a0, a1); }
    }
#pragma unroll
    for (int h = 0; h < 16; ++h) {
      const float4 w = *(const float4*)(Wo1 + h*4);
      f2 a = spl(bo1[h]);
      a = spl(w.x)*ch2[0] + a; a = spl(w.y)*ch2[1] + a;
      a = spl(w.z)*ch2[2] + a; a = spl(w.w)*ch2[3] + a;
      a.x = fmaxf(a.x, 0.f); a.y = fmaxf(a.y, 0.f);
      if (h < 8) opl2[h] = a;
      else { float a0 = a.x, a1 = a.y; BFLY3(a0, a1); RED_W(32 + (h-8)*4, a0, a1); }
    }
#pragma unroll
    for (int j = 0; j < 8; ++j) {
      const float s2 = opl2[j].x + opl2[j].y;
      const float s4 = s2 + __shfl_xor(s2, 1, 64);
      ol2[j] = (spl(s4) - opl2[j]) * spl(1.f/3.f);
    }
  }
  PUBLISH(0, 1)

  // ---------------- layers 1..6 (Cin = 36) ----------------
  for (int L = 1; L < 7; ++L) {
    const float* __restrict__ wEl = We + (L-1)*576;   // wave-uniform -> s_loads
    const float* __restrict__ wOl = Wo + (L-1)*576;
    const int par_r = (L-1) & 1;
    const int par_w = L & 1;
    const int bb    = L & 1;       // bias parity buffer

    // --- phase 1: EGO conv, no bias (16 f2 cross the fold barrier) ---
    f2 accE2[16];
#pragma unroll
    for (int h = 0; h < 16; ++h) {
      const float4* wr = (const float4*)(wEl + h*36);
      const float4 w0 = wr[0], w1 = wr[1], w2 = wr[2], w5 = wr[5], w6 = wr[6];
      DOT20B(accE2[h], w0, w1, w2, w5, w6, spl(0.f))
    }

    // --- wave15: spin on b-group, gather means, fold BOTH bias sets ---
    if (wv == 15) {
      SPIN_RELAXED(L)
      float s = 0.f;
#pragma unroll
      for (int k = 0; k < 4; ++k)
        s += __hip_atomic_load(&part[((par_r*64 + b)*4 + k)*64 + lane],
                               __ATOMIC_RELAXED, __HIP_MEMORY_SCOPE_AGENT);
      gv[lane] = s * (1.f/2048.f);
      // same-wave LDS RAW (r11-verified): lane owns (u,h), folds both convs
      const int u = lane & 3;
      const int h = lane >> 2;
      float bE = be[(L-1)*16 + h];
      float bO = bo[(L-1)*16 + h];
#pragma unroll
      for (int j = 0; j < 8; ++j) {
        const float eg = gv[j*4 + u];
        const float so = gv[32+j*4+0] + gv[32+j*4+1] + gv[32+j*4+2] + gv[32+j*4+3];
        const float og = (so - gv[32 + j*4 + u]) * (1.f/3.f);
        bE += wEl[h*36 + 12 + j] * eg + wEl[h*36 + 28 + j] * og;
        bO += wOl[h*36 + 12 + j] * eg + wOl[h*36 + 28 + j] * og;
      }
      biasE[bb][h][u] = bE;
      biasO[bb][h][u] = bO;
    }
    __syncthreads();   // barrier 1: biases ready

    // --- finish ego HI (stats-only rows) + opp HI conv -> publish early ---
#pragma unroll
    for (int h = 8; h < 16; ++h) {
      f2 a = accE2[h] + *(const f2*)&biasE[bb][h][2*p];
      float a0 = fmaxf(a.x, 0.f), a1 = fmaxf(a.y, 0.f);
      BFLY3(a0, a1); RED_W((h-8)*4, a0, a1);
    }
#pragma unroll
    for (int h = 8; h < 16; ++h) {
      const float4* wr = (const float4*)(wOl + h*36);
      const float4 w0 = wr[0], w1 = wr[1], w2 = wr[2], w5 = wr[5], w6 = wr[6];
      f2 a;
      DOT20B(a, w0, w1, w2, w5, w6, *(const f2*)&biasO[bb][h][2*p])
      float a0 = fmaxf(a.x, 0.f), a1 = fmaxf(a.y, 0.f);
      BFLY3(a0, a1); RED_W(32 + (h-8)*4, a0, a1);
    }
    PUBLISH(par_w, L + 1)   // barrier 2 + wave0 publish + flag (early)

    // --- lo halves in the flag-propagation shadow ---
    f2 eln2[8];
#pragma unroll
    for (int h = 0; h < 8; ++h) {
      f2 a = accE2[h] + *(const f2*)&biasE[bb][h][2*p];
      a.x = fmaxf(a.x, 0.f); a.y = fmaxf(a.y, 0.f);
      eln2[h] = a;
    }
    f2 opl2[8];
#pragma unroll
    for (int h = 0; h < 8; ++h) {
      const float4* wr = (const float4*)(wOl + h*36);
      const float4 w0 = wr[0], w1 = wr[1], w2 = wr[2], w5 = wr[5], w6 = wr[6];
      f2 a;
      DOT20B(a, w0, w1, w2, w5, w6, *(const f2*)&biasO[bb][h][2*p])
      a.x = fmaxf(a.x, 0.f); a.y = fmaxf(a.y, 0.f);
      opl2[h] = a;
    }
#pragma unroll
    for (int j = 0; j < 8; ++j) {
      const float s2 = opl2[j].x + opl2[j].y;
      const float s4 = s2 + __shfl_xor(s2, 1, 64);
      ol2[j] = (spl(s4) - opl2[j]) * spl(1.f/3.f);
      el2[j] = eln2[j];
    }
  }

  // ---------------- final 1x1 conv + mean over users ----------------
  if (wv == 0) {   // layer 6 wrote parity 0, flag 7
    SPIN_RELAXED(7)
    float s = 0.f;
#pragma unroll
    for (int k = 0; k < 4; ++k)
      s += __hip_atomic_load(&part[((0*64 + b)*4 + k)*64 + lane],
                             __ATOMIC_RELAXED, __HIP_MEMORY_SCOPE_AGENT);
    gv[lane] = s * (1.f/2048.f);
    if (lane == 0) {
      float sf = b8[0];
#pragma unroll
      for (int j = 0; j < 8; ++j) {
        const float so = gv[32+j*4+0] + gv[32+j*4+1] + gv[32+j*4+2] + gv[32+j*4+3];
#pragma unroll
        for (int u = 0; u < 4; ++u) {
          const float eg = gv[j*4 + u];
          const float og = (so - gv[32 + j*4 + u]) * (1.f/3.f);
          sf += 0.25f * (W8[12 + j] * eg + W8[28 + j] * og);
        }
      }
      fin = sf;
    }
  }
  __syncthreads();
  f2 v = spl(0.f);
#pragma unroll
  for (int c = 0; c < 4; ++c) v = spl(W8[c]) * ch2[c] + v;
#pragma unroll
  for (int j = 0; j < 8; ++j) {
    v = spl(W8[4 + j]) * el2[j] + v;
    v = spl(W8[20 + j]) * ol2[j] + v;
  }
  float t = v.x + v.y;
  t += __shfl_xor(t, 1, 64);   // sum over all 4 users
  if (p == 0)
    out[b*2048 + n] = (fin + 0.25f * t) * 3.14159265358979f;
}

extern "C" void kernel_launch(void* const* d_in, const int* in_sizes, int n_in,
                              void* d_out, int out_size, void* d_ws, size_t ws_size,
                              hipStream_t stream) {
  const float* channel = (const float*)d_in[0];
  const float* We1 = (const float*)d_in[1];
  const float* be1 = (const float*)d_in[2];
  const float* We  = (const float*)d_in[3];
  const float* be  = (const float*)d_in[4];
  const float* Wo1 = (const float*)d_in[5];
  const float* bo1 = (const float*)d_in[6];
  const float* Wo  = (const float*)d_in[7];
  const float* bo  = (const float*)d_in[8];
  const float* W8  = (const float*)d_in[9];
  const float* b8  = (const float*)d_in[10];
  float* out  = (float*)d_out;
  float* part = (float*)d_ws;                       // 2*64*4*64 floats = 131072 B
  int*   flags = (int*)((char*)d_ws + 131072);      // 256 ints

  void* args[] = { (void*)&channel, (void*)&We1, (void*)&be1, (void*)&We, (void*)&be,
                   (void*)&Wo1, (void*)&bo1, (void*)&Wo, (void*)&bo,
                   (void*)&W8, (void*)&b8, (void*)&out, (void*)&part, (void*)&flags };
  hipLaunchCooperativeKernel((void*)risnet_kernel, dim3(GRID), dim3(TPB), args, 0, stream);
}

// Round 21
// 127.200 us; speedup vs baseline: 3.1962x; 1.0451x over previous
//
#include <hip/hip_runtime.h>
#include <hip/hip_cooperative_groups.h>

namespace cg = cooperative_groups;

#define TPB 1024
#define GRID 256   // coop capacity on this stack is <=256 blocks (r2/r7). Never exceed.

// r20 post-mortem: fence-free protocol works (133us, WRITE clean). Remaining
// stall ~83us: (a) initial cg grid.sync (~10-25us) kept only for flag-zero
// replay safety; (b) 4-address flag poll per layer. r21: (1) zero sync state
// with hipMemsetAsync on the stream BEFORE the kernel (graph-capturable,
// stream-ordered) -> delete grid.sync entirely; (2) single group counter:
// producers atomicAdd(&gcnt[b],1) after vmcnt drain; consumer polls ONE
// address until gcnt[b] >= 4L. Compute identical to r20.

typedef float f2 __attribute__((ext_vector_type(2)));
static __device__ __forceinline__ f2 spl(float s) { f2 r; r.x = s; r.y = s; return r; }

__global__ void risnet_kernel(
    const float* __restrict__ channel,
    const float* __restrict__ We1, const float* __restrict__ be1,
    const float* __restrict__ We,  const float* __restrict__ be,
    const float* __restrict__ Wo1, const float* __restrict__ bo1,
    const float* __restrict__ Wo,  const float* __restrict__ bo,
    const float* __restrict__ W8,  const float* __restrict__ b8,
    float* __restrict__ out, float* __restrict__ part, int* __restrict__ gcnt)
{
  const int tid   = threadIdx.x;
  const int lane  = tid & 63;
  const int wv    = tid >> 6;                 // 0..15
  const int p     = tid & 1;                  // user-half: owns users 2p, 2p+1
  const int B     = blockIdx.x;
  const int b     = (B & 7) * 8 + ((B >> 3) & 7);  // same B%8 (XCD) per b-group (perf)
  const int chunk = B >> 6;                   // 0..3
  const int n     = (chunk << 9) | (tid >> 1);// 0..2047

  __shared__ __align__(16) float biasE[2][16][4];  // [L&1][h][u] parity dbuf
  __shared__ __align__(16) float biasO[2][16][4];
  __shared__ float red[64][64];                 // [row=wv*4+grp][conv*32+j*4+u]
  __shared__ float gv[64];                      // per-b means: ego-g 0..31, opp-g 32..63
  __shared__ float fin;

  // per-thread channel slice, packed over the user pair: ch2[f] = {u=2p, u=2p+1}
  f2 ch2[4];
#pragma unroll
  for (int f = 0; f < 4; ++f) {
    ch2[f].x = channel[((b*4 + 2*p + 0)*4 + f)*2048 + n];
    ch2[f].y = channel[((b*4 + 2*p + 1)*4 + f)*2048 + n];
  }

  f2 el2[8], ol2[8];

#define BFLY3(a0, a1) { \
  a0 += __shfl_xor(a0, 2, 64);  a1 += __shfl_xor(a1, 2, 64);  \
  a0 += __shfl_xor(a0, 4, 64);  a1 += __shfl_xor(a1, 4, 64);  \
  a0 += __shfl_xor(a0, 8, 64);  a1 += __shfl_xor(a1, 8, 64); }

#define RED_W(base_col, a0, a1) \
  if ((lane & 15) < 2) { \
    red[(wv<<2)|(lane>>4)][(base_col) + 2*(lane&1) + 0] = a0; \
    red[(wv<<2)|(lane>>4)][(base_col) + 2*(lane&1) + 1] = a1; }

// publish: wave0 sums red columns, atomically stores part (coherence-point
// write, no cache walk), drains vmcnt, then atomicAdd +1 on the group counter.
#define PUBLISH(Lpar) { \
  __syncthreads(); \
  if (tid < 64) { \
    float s0 = 0.f, s1 = 0.f, s2 = 0.f, s3 = 0.f; \
    _Pragma("unroll") for (int r = 0; r < 64; r += 4) { \
      s0 += red[r+0][tid]; s1 += red[r+1][tid]; \
      s2 += red[r+2][tid]; s3 += red[r+3][tid]; \
    } \
    __hip_atomic_store(&part[(((Lpar)*64 + b)*4 + chunk)*64 + tid], \
                       (s0+s1)+(s2+s3), \
                       __ATOMIC_RELAXED, __HIP_MEMORY_SCOPE_AGENT); \
    asm volatile("s_waitcnt vmcnt(0)" ::: "memory"); \
    if (lane == 0) \
      __hip_atomic_fetch_add(&gcnt[b], 1, __ATOMIC_RELAXED, __HIP_MEMORY_SCOPE_AGENT); \
  } }

  // single-address relaxed spin; compiler barrier after (part reads are
  // agent-atomic loads issued after the poll breaks -> coherence point)
#define SPIN_CNT(tgt) { \
  for (;;) { \
    int c = __hip_atomic_load(&gcnt[b], __ATOMIC_RELAXED, __HIP_MEMORY_SCOPE_AGENT); \
    if (c >= (tgt)) break; \
    __builtin_amdgcn_s_sleep(1); \
  } \
  asm volatile("" ::: "memory"); }

  // packed 20-col dot product (ch 0..3, el 4..11, ol 20..27), BINIT = bias or 0
#define DOT20B(ACC, W0, W1, W2, W5, W6, BINIT) { \
  f2 v = (BINIT); \
  v = spl(W0.x)*ch2[0] + v; v = spl(W0.y)*ch2[1] + v; \
  v = spl(W0.z)*ch2[2] + v; v = spl(W0.w)*ch2[3] + v; \
  v = spl(W1.x)*el2[0] + v; v = spl(W1.y)*el2[1] + v; \
  v = spl(W1.z)*el2[2] + v; v = spl(W1.w)*el2[3] + v; \
  v = spl(W2.x)*el2[4] + v; v = spl(W2.y)*el2[5] + v; \
  v = spl(W2.z)*el2[6] + v; v = spl(W2.w)*el2[7] + v; \
  v = spl(W5.x)*ol2[0] + v; v = spl(W5.y)*ol2[1] + v; \
  v = spl(W5.z)*ol2[2] + v; v = spl(W5.w)*ol2[3] + v; \
  v = spl(W6.x)*ol2[4] + v; v = spl(W6.y)*ol2[5] + v; \
  v = spl(W6.z)*ol2[6] + v; v = spl(W6.w)*ol2[7] + v; \
  ACC = v; }

  // ---------------- layer 0 (Cin = 4, feats = ch) ----------------
  {
    f2 opl2[8];
#pragma unroll
    for (int h = 0; h < 16; ++h) {
      const float4 w = *(const float4*)(We1 + h*4);
      f2 a = spl(be1[h]);
      a = spl(w.x)*ch2[0] + a; a = spl(w.y)*ch2[1] + a;
      a = spl(w.z)*ch2[2] + a; a = spl(w.w)*ch2[3] + a;
      a.x = fmaxf(a.x, 0.f); a.y = fmaxf(a.y, 0.f);
      if (h < 8) el2[h] = a;
      else { float a0 = a.x, a1 = a.y; BFLY3(a0, a1); RED_W((h-8)*4, a0, a1); }
    }
#pragma unroll
    for (int h = 0; h < 16; ++h) {
      const float4 w = *(const float4*)(Wo1 + h*4);
      f2 a = spl(bo1[h]);
      a = spl(w.x)*ch2[0] + a; a = spl(w.y)*ch2[1] + a;
      a = spl(w.z)*ch2[2] + a; a = spl(w.w)*ch2[3] + a;
      a.x = fmaxf(a.x, 0.f); a.y = fmaxf(a.y, 0.f);
      if (h < 8) opl2[h] = a;
      else { float a0 = a.x, a1 = a.y; BFLY3(a0, a1); RED_W(32 + (h-8)*4, a0, a1); }
    }
#pragma unroll
    for (int j = 0; j < 8; ++j) {
      const float s2 = opl2[j].x + opl2[j].y;
      const float s4 = s2 + __shfl_xor(s2, 1, 64);
      ol2[j] = (spl(s4) - opl2[j]) * spl(1.f/3.f);
    }
  }
  PUBLISH(0)

  // ---------------- layers 1..6 (Cin = 36) ----------------
  for (int L = 1; L < 7; ++L) {
    const float* __restrict__ wEl = We + (L-1)*576;   // wave-uniform -> s_loads
    const float* __restrict__ wOl = Wo + (L-1)*576;
    const int par_r = (L-1) & 1;
    const int par_w = L & 1;
    const int bb    = L & 1;       // bias parity buffer

    // --- phase 1: EGO conv, no bias (16 f2 cross the fold barrier) ---
    f2 accE2[16];
#pragma unroll
    for (int h = 0; h < 16; ++h) {
      const float4* wr = (const float4*)(wEl + h*36);
      const float4 w0 = wr[0], w1 = wr[1], w2 = wr[2], w5 = wr[5], w6 = wr[6];
      DOT20B(accE2[h], w0, w1, w2, w5, w6, spl(0.f))
    }

    // --- wave15: spin on group counter, gather means, fold BOTH bias sets ---
    if (wv == 15) {
      SPIN_CNT(4*L)
      float s = 0.f;
#pragma unroll
      for (int k = 0; k < 4; ++k)
        s += __hip_atomic_load(&part[((par_r*64 + b)*4 + k)*64 + lane],
                               __ATOMIC_RELAXED, __HIP_MEMORY_SCOPE_AGENT);
      gv[lane] = s * (1.f/2048.f);
      // same-wave LDS RAW (r11-verified): lane owns (u,h), folds both convs
      const int u = lane & 3;
      const int h = lane >> 2;
      float bE = be[(L-1)*16 + h];
      float bO = bo[(L-1)*16 + h];
#pragma unroll
      for (int j = 0; j < 8; ++j) {
        const float eg = gv[j*4 + u];
        const float so = gv[32+j*4+0] + gv[32+j*4+1] + gv[32+j*4+2] + gv[32+j*4+3];
        const float og = (so - gv[32 + j*4 + u]) * (1.f/3.f);
        bE += wEl[h*36 + 12 + j] * eg + wEl[h*36 + 28 + j] * og;
        bO += wOl[h*36 + 12 + j] * eg + wOl[h*36 + 28 + j] * og;
      }
      biasE[bb][h][u] = bE;
      biasO[bb][h][u] = bO;
    }
    __syncthreads();   // barrier 1: biases ready

    // --- finish ego HI (stats-only rows) + opp HI conv -> publish early ---
#pragma unroll
    for (int h = 8; h < 16; ++h) {
      f2 a = accE2[h] + *(const f2*)&biasE[bb][h][2*p];
      float a0 = fmaxf(a.x, 0.f), a1 = fmaxf(a.y, 0.f);
      BFLY3(a0, a1); RED_W((h-8)*4, a0, a1);
    }
#pragma unroll
    for (int h = 8; h < 16; ++h) {
      const float4* wr = (const float4*)(wOl + h*36);
      const float4 w0 = wr[0], w1 = wr[1], w2 = wr[2], w5 = wr[5], w6 = wr[6];
      f2 a;
      DOT20B(a, w0, w1, w2, w5, w6, *(const f2*)&biasO[bb][h][2*p])
      float a0 = fmaxf(a.x, 0.f), a1 = fmaxf(a.y, 0.f);
      BFLY3(a0, a1); RED_W(32 + (h-8)*4, a0, a1);
    }
    PUBLISH(par_w)   // barrier 2 + wave0 publish + counter (early)

    // --- lo halves in the propagation shadow ---
    f2 eln2[8];
#pragma unroll
    for (int h = 0; h < 8; ++h) {
      f2 a = accE2[h] + *(const f2*)&biasE[bb][h][2*p];
      a.x = fmaxf(a.x, 0.f); a.y = fmaxf(a.y, 0.f);
      eln2[h] = a;
    }
    f2 opl2[8];
#pragma unroll
    for (int h = 0; h < 8; ++h) {
      const float4* wr = (const float4*)(wOl + h*36);
      const float4 w0 = wr[0], w1 = wr[1], w2 = wr[2], w5 = wr[5], w6 = wr[6];
      f2 a;
      DOT20B(a, w0, w1, w2, w5, w6, *(const f2*)&biasO[bb][h][2*p])
      a.x = fmaxf(a.x, 0.f); a.y = fmaxf(a.y, 0.f);
      opl2[h] = a;
    }
#pragma unroll
    for (int j = 0; j < 8; ++j) {
      const float s2 = opl2[j].x + opl2[j].y;
      const float s4 = s2 + __shfl_xor(s2, 1, 64);
      ol2[j] = (spl(s4) - opl2[j]) * spl(1.f/3.f);
      el2[j] = eln2[j];
    }
  }

  // ---------------- final 1x1 conv + mean over users ----------------
  if (wv == 0) {   // layer 6 wrote parity 0; all 7 publishes from 4 blocks = 28
    SPIN_CNT(28)
    float s = 0.f;
#pragma unroll
    for (int k = 0; k < 4; ++k)
      s += __hip_atomic_load(&part[((0*64 + b)*4 + k)*64 + lane],
                             __ATOMIC_RELAXED, __HIP_MEMORY_SCOPE_AGENT);
    gv[lane] = s * (1.f/2048.f);
    if (lane == 0) {
      float sf = b8[0];
#pragma unroll
      for (int j = 0; j < 8; ++j) {
        const float so = gv[32+j*4+0] + gv[32+j*4+1] + gv[32+j*4+2] + gv[32+j*4+3];
#pragma unroll
        for (int u = 0; u < 4; ++u) {
          const float eg = gv[j*4 + u];
          const float og = (so - gv[32 + j*4 + u]) * (1.f/3.f);
          sf += 0.25f * (W8[12 + j] * eg + W8[28 + j] * og);
        }
      }
      fin = sf;
    }
  }
  __syncthreads();
  f2 v = spl(0.f);
#pragma unroll
  for (int c = 0; c < 4; ++c) v = spl(W8[c]) * ch2[c] + v;
#pragma unroll
  for (int j = 0; j < 8; ++j) {
    v = spl(W8[4 + j]) * el2[j] + v;
    v = spl(W8[20 + j]) * ol2[j] + v;
  }
  float t = v.x + v.y;
  t += __shfl_xor(t, 1, 64);   // sum over all 4 users
  if (p == 0)
    out[b*2048 + n] = (fin + 0.25f * t) * 3.14159265358979f;
}

extern "C" void kernel_launch(void* const* d_in, const int* in_sizes, int n_in,
                              void* d_out, int out_size, void* d_ws, size_t ws_size,
                              hipStream_t stream) {
  const float* channel = (const float*)d_in[0];
  const float* We1 = (const float*)d_in[1];
  const float* be1 = (const float*)d_in[2];
  const float* We  = (const float*)d_in[3];
  const float* be  = (const float*)d_in[4];
  const float* Wo1 = (const float*)d_in[5];
  const float* bo1 = (const float*)d_in[6];
  const float* Wo  = (const float*)d_in[7];
  const float* bo  = (const float*)d_in[8];
  const float* W8  = (const float*)d_in[9];
  const float* b8  = (const float*)d_in[10];
  float* out  = (float*)d_out;
  float* part = (float*)d_ws;                       // 2*64*4*64 floats = 131072 B
  int*   gcnt = (int*)((char*)d_ws + 131072);       // 64 ints

  // stream-ordered zeroing of the group counters: completes before the kernel
  // starts (replaces the in-kernel grid.sync + zeroing). Graph-capturable.
  hipMemsetAsync(gcnt, 0, 64 * sizeof(int), stream);

  void* args[] = { (void*)&channel, (void*)&We1, (void*)&be1, (void*)&We, (void*)&be,
                   (void*)&Wo1, (void*)&bo1, (void*)&Wo, (void*)&bo,
                   (void*)&W8, (void*)&b8, (void*)&out, (void*)&part, (void*)&gcnt };
  hipLaunchCooperativeKernel((void*)risnet_kernel, dim3(GRID), dim3(TPB), args, 0, stream);
}

// Round 22
// 119.135 us; speedup vs baseline: 3.4125x; 1.0677x over previous
//
#include <hip/hip_runtime.h>
#include <hip/hip_cooperative_groups.h>

#define TPB 1024
#define GRID 256   // coop capacity on this stack is <=256 blocks (r2/r7). Never exceed.

// r21 post-mortem: 127us; ~10us/layer protocol left = barrier2 (red[] ordering
// rendezvous) + 4-row gather. r22 (protocol only, compute identical):
// (1) barrier2 deleted -> cumulative LDS wave-counter; wave0 polls to 16*epoch
//     and publishes while other waves run ahead (red reuse safe: own-rows +
//     barrier1(L+1) ordering).
// (2) part rows are CUMULATIVE per parity: producers unsafeAtomicAdd their
//     column sums; consumer reads ONE row, delta vs register cum0/cum1.
//     Parity proof: publish(L+2)->parity row gated on gcnt>=4(L+2) which
//     implies all stats(L) reads done. part+gcnt zeroed by stream memset.
// (3) final gather by wave15 (holds cum).

typedef float f2 __attribute__((ext_vector_type(2)));
static __device__ __forceinline__ f2 spl(float s) { f2 r; r.x = s; r.y = s; return r; }

__global__ void risnet_kernel(
    const float* __restrict__ channel,
    const float* __restrict__ We1, const float* __restrict__ be1,
    const float* __restrict__ We,  const float* __restrict__ be,
    const float* __restrict__ Wo1, const float* __restrict__ bo1,
    const float* __restrict__ Wo,  const float* __restrict__ bo,
    const float* __restrict__ W8,  const float* __restrict__ b8,
    float* __restrict__ out, float* __restrict__ part, int* __restrict__ gcnt)
{
  const int tid   = threadIdx.x;
  const int lane  = tid & 63;
  const int wv    = tid >> 6;                 // 0..15
  const int p     = tid & 1;                  // user-half: owns users 2p, 2p+1
  const int B     = blockIdx.x;
  const int b     = (B & 7) * 8 + ((B >> 3) & 7);  // same B%8 (XCD) per b-group (perf)
  const int chunk = B >> 6;                   // 0..3
  const int n     = (chunk << 9) | (tid >> 1);// 0..2047

  __shared__ __align__(16) float biasE[2][16][4];  // [L&1][h][u] parity dbuf
  __shared__ __align__(16) float biasO[2][16][4];
  __shared__ float red[64][64];                 // [row=wv*4+grp][conv*32+j*4+u]
  __shared__ float gv[64];                      // per-b mean deltas (wave15 only)
  __shared__ float fin;
  __shared__ int   lcnt;                        // cumulative per-wave publish count

  if (tid == 0) lcnt = 0;

  // per-thread channel slice, packed over the user pair: ch2[f] = {u=2p, u=2p+1}
  f2 ch2[4];
#pragma unroll
  for (int f = 0; f < 4; ++f) {
    ch2[f].x = channel[((b*4 + 2*p + 0)*4 + f)*2048 + n];
    ch2[f].y = channel[((b*4 + 2*p + 1)*4 + f)*2048 + n];
  }
  __syncthreads();   // lcnt init visible before any WAVE_DONE

  f2 el2[8], ol2[8];
  float cum0 = 0.f, cum1 = 0.f;   // wave15: cumulative part-row values per parity
  int   pubt = 16;                // wave0: LDS-counter target for next publish

#define BFLY3(a0, a1) { \
  a0 += __shfl_xor(a0, 2, 64);  a1 += __shfl_xor(a1, 2, 64);  \
  a0 += __shfl_xor(a0, 4, 64);  a1 += __shfl_xor(a1, 4, 64);  \
  a0 += __shfl_xor(a0, 8, 64);  a1 += __shfl_xor(a1, 8, 64); }

#define RED_W(base_col, a0, a1) \
  if ((lane & 15) < 2) { \
    red[(wv<<2)|(lane>>4)][(base_col) + 2*(lane&1) + 0] = a0; \
    red[(wv<<2)|(lane>>4)][(base_col) + 2*(lane&1) + 1] = a1; }

  // this wave's red[] rows for the current epoch are complete
#define WAVE_DONE() { \
  asm volatile("s_waitcnt lgkmcnt(0)" ::: "memory"); \
  if (lane == 0) \
    __hip_atomic_fetch_add(&lcnt, 1, __ATOMIC_RELAXED, __HIP_MEMORY_SCOPE_WORKGROUP); }

  // wave0: poll LDS counter to epoch target, column-sum red, atomicAdd into
  // the CUMULATIVE parity row, drain, bump group counter. No block barrier.
#define PUBLISH_W0(par) \
  if (wv == 0) { \
    for (;;) { \
      int c = __hip_atomic_load(&lcnt, __ATOMIC_RELAXED, __HIP_MEMORY_SCOPE_WORKGROUP); \
      if (c >= pubt) break; \
      __builtin_amdgcn_s_sleep(0); \
    } \
    asm volatile("" ::: "memory"); \
    float s0 = 0.f, s1 = 0.f, s2 = 0.f, s3 = 0.f; \
    _Pragma("unroll") for (int r = 0; r < 64; r += 4) { \
      s0 += red[r+0][lane]; s1 += red[r+1][lane]; \
      s2 += red[r+2][lane]; s3 += red[r+3][lane]; \
    } \
    unsafeAtomicAdd(&part[((par)*64 + b)*64 + lane], (s0+s1)+(s2+s3)); \
    asm volatile("s_waitcnt vmcnt(0)" ::: "memory"); \
    if (lane == 0) \
      __hip_atomic_fetch_add(&gcnt[b], 1, __ATOMIC_RELAXED, __HIP_MEMORY_SCOPE_AGENT); \
  } \
  pubt += 16;

  // single-address relaxed spin on the group counter
#define SPIN_CNT(tgt) { \
  for (;;) { \
    int c = __hip_atomic_load(&gcnt[b], __ATOMIC_RELAXED, __HIP_MEMORY_SCOPE_AGENT); \
    if (c >= (tgt)) break; \
    __builtin_amdgcn_s_sleep(1); \
  } \
  asm volatile("" ::: "memory"); }

  // packed 20-col dot product (ch 0..3, el 4..11, ol 20..27), BINIT = bias or 0
#define DOT20B(ACC, W0, W1, W2, W5, W6, BINIT) { \
  f2 v = (BINIT); \
  v = spl(W0.x)*ch2[0] + v; v = spl(W0.y)*ch2[1] + v; \
  v = spl(W0.z)*ch2[2] + v; v = spl(W0.w)*ch2[3] + v; \
  v = spl(W1.x)*el2[0] + v; v = spl(W1.y)*el2[1] + v; \
  v = spl(W1.z)*el2[2] + v; v = spl(W1.w)*el2[3] + v; \
  v = spl(W2.x)*el2[4] + v; v = spl(W2.y)*el2[5] + v; \
  v = spl(W2.z)*el2[6] + v; v = spl(W2.w)*el2[7] + v; \
  v = spl(W5.x)*ol2[0] + v; v = spl(W5.y)*ol2[1] + v; \
  v = spl(W5.z)*ol2[2] + v; v = spl(W5.w)*ol2[3] + v; \
  v = spl(W6.x)*ol2[4] + v; v = spl(W6.y)*ol2[5] + v; \
  v = spl(W6.z)*ol2[6] + v; v = spl(W6.w)*ol2[7] + v; \
  ACC = v; }

  // ---------------- layer 0 (Cin = 4, feats = ch) ----------------
  {
    f2 opl2[8];
#pragma unroll
    for (int h = 0; h < 16; ++h) {
      const float4 w = *(const float4*)(We1 + h*4);
      f2 a = spl(be1[h]);
      a = spl(w.x)*ch2[0] + a; a = spl(w.y)*ch2[1] + a;
      a = spl(w.z)*ch2[2] + a; a = spl(w.w)*ch2[3] + a;
      a.x = fmaxf(a.x, 0.f); a.y = fmaxf(a.y, 0.f);
      if (h < 8) el2[h] = a;
      else { float a0 = a.x, a1 = a.y; BFLY3(a0, a1); RED_W((h-8)*4, a0, a1); }
    }
#pragma unroll
    for (int h = 0; h < 16; ++h) {
      const float4 w = *(const float4*)(Wo1 + h*4);
      f2 a = spl(bo1[h]);
      a = spl(w.x)*ch2[0] + a; a = spl(w.y)*ch2[1] + a;
      a = spl(w.z)*ch2[2] + a; a = spl(w.w)*ch2[3] + a;
      a.x = fmaxf(a.x, 0.f); a.y = fmaxf(a.y, 0.f);
      if (h < 8) opl2[h] = a;
      else { float a0 = a.x, a1 = a.y; BFLY3(a0, a1); RED_W(32 + (h-8)*4, a0, a1); }
    }
    WAVE_DONE()
    PUBLISH_W0(0)
#pragma unroll
    for (int j = 0; j < 8; ++j) {
      const float s2 = opl2[j].x + opl2[j].y;
      const float s4 = s2 + __shfl_xor(s2, 1, 64);
      ol2[j] = (spl(s4) - opl2[j]) * spl(1.f/3.f);
    }
  }

  // ---------------- layers 1..6 (Cin = 36) ----------------
  for (int L = 1; L < 7; ++L) {
    const float* __restrict__ wEl = We + (L-1)*576;   // wave-uniform -> s_loads
    const float* __restrict__ wOl = Wo + (L-1)*576;
    const int pr = (L-1) & 1;      // parity row holding stats(L-1) cumulative
    const int pw = L & 1;          // parity row this layer publishes into
    const int bb = L & 1;          // bias parity buffer

    // --- phase 1: EGO conv, no bias (16 f2 cross the fold barrier) ---
    f2 accE2[16];
#pragma unroll
    for (int h = 0; h < 16; ++h) {
      const float4* wr = (const float4*)(wEl + h*36);
      const float4 w0 = wr[0], w1 = wr[1], w2 = wr[2], w5 = wr[5], w6 = wr[6];
      DOT20B(accE2[h], w0, w1, w2, w5, w6, spl(0.f))
    }

    // --- wave15: spin on group counter, read ONE cumulative row, delta, fold ---
    if (wv == 15) {
      SPIN_CNT(4*L)
      float R = __hip_atomic_load(&part[(pr*64 + b)*64 + lane],
                                  __ATOMIC_RELAXED, __HIP_MEMORY_SCOPE_AGENT);
      float prev = pr ? cum1 : cum0;
      float d = R - prev;
      if (pr) cum1 = R; else cum0 = R;
      gv[lane] = d * (1.f/2048.f);
      // same-wave LDS RAW (r11-verified): lane owns (u,h), folds both convs
      const int u = lane & 3;
      const int h = lane >> 2;
      float bE = be[(L-1)*16 + h];
      float bO = bo[(L-1)*16 + h];
#pragma unroll
      for (int j = 0; j < 8; ++j) {
        const float eg = gv[j*4 + u];
        const float so = gv[32+j*4+0] + gv[32+j*4+1] + gv[32+j*4+2] + gv[32+j*4+3];
        const float og = (so - gv[32 + j*4 + u]) * (1.f/3.f);
        bE += wEl[h*36 + 12 + j] * eg + wEl[h*36 + 28 + j] * og;
        bO += wOl[h*36 + 12 + j] * eg + wOl[h*36 + 28 + j] * og;
      }
      biasE[bb][h][u] = bE;
      biasO[bb][h][u] = bO;
    }
    __syncthreads();   // the ONLY block barrier this layer: biases ready

    // --- finish ego HI (stats-only rows) + opp HI conv -> per-wave done ---
#pragma unroll
    for (int h = 8; h < 16; ++h) {
      f2 a = accE2[h] + *(const f2*)&biasE[bb][h][2*p];
      float a0 = fmaxf(a.x, 0.f), a1 = fmaxf(a.y, 0.f);
      BFLY3(a0, a1); RED_W((h-8)*4, a0, a1);
    }
#pragma unroll
    for (int h = 8; h < 16; ++h) {
      const float4* wr = (const float4*)(wOl + h*36);
      const float4 w0 = wr[0], w1 = wr[1], w2 = wr[2], w5 = wr[5], w6 = wr[6];
      f2 a;
      DOT20B(a, w0, w1, w2, w5, w6, *(const f2*)&biasO[bb][h][2*p])
      float a0 = fmaxf(a.x, 0.f), a1 = fmaxf(a.y, 0.f);
      BFLY3(a0, a1); RED_W(32 + (h-8)*4, a0, a1);
    }
    WAVE_DONE()
    PUBLISH_W0(pw)   // wave0 publishes; other waves fall through to lo halves

    // --- lo halves in the propagation shadow ---
    f2 eln2[8];
#pragma unroll
    for (int h = 0; h < 8; ++h) {
      f2 a = accE2[h] + *(const f2*)&biasE[bb][h][2*p];
      a.x = fmaxf(a.x, 0.f); a.y = fmaxf(a.y, 0.f);
      eln2[h] = a;
    }
    f2 opl2[8];
#pragma unroll
    for (int h = 0; h < 8; ++h) {
      const float4* wr = (const float4*)(wOl + h*36);
      const float4 w0 = wr[0], w1 = wr[1], w2 = wr[2], w5 = wr[5], w6 = wr[6];
      f2 a;
      DOT20B(a, w0, w1, w2, w5, w6, *(const f2*)&biasO[bb][h][2*p])
      a.x = fmaxf(a.x, 0.f); a.y = fmaxf(a.y, 0.f);
      opl2[h] = a;
    }
#pragma unroll
    for (int j = 0; j < 8; ++j) {
      const float s2 = opl2[j].x + opl2[j].y;
      const float s4 = s2 + __shfl_xor(s2, 1, 64);
      ol2[j] = (spl(s4) - opl2[j]) * spl(1.f/3.f);
      el2[j] = eln2[j];
    }
  }

  // ---------------- final 1x1 conv + mean over users ----------------
  if (wv == 15) {   // layer 6 published parity 0; 7 publishes x 4 blocks = 28
    SPIN_CNT(28)
    float R = __hip_atomic_load(&part[(0*64 + b)*64 + lane],
                                __ATOMIC_RELAXED, __HIP_MEMORY_SCOPE_AGENT);
    gv[lane] = (R - cum0) * (1.f/2048.f);
    if (lane == 0) {
      float sf = b8[0];
#pragma unroll
      for (int j = 0; j < 8; ++j) {
        const float so = gv[32+j*4+0] + gv[32+j*4+1] + gv[32+j*4+2] + gv[32+j*4+3];
#pragma unroll
        for (int u = 0; u < 4; ++u) {
          const float eg = gv[j*4 + u];
          const float og = (so - gv[32 + j*4 + u]) * (1.f/3.f);
          sf += 0.25f * (W8[12 + j] * eg + W8[28 + j] * og);
        }
      }
      fin = sf;
    }
  }
  __syncthreads();
  f2 v = spl(0.f);
#pragma unroll
  for (int c = 0; c < 4; ++c) v = spl(W8[c]) * ch2[c] + v;
#pragma unroll
  for (int j = 0; j < 8; ++j) {
    v = spl(W8[4 + j]) * el2[j] + v;
    v = spl(W8[20 + j]) * ol2[j] + v;
  }
  float t = v.x + v.y;
  t += __shfl_xor(t, 1, 64);   // sum over all 4 users
  if (p == 0)
    out[b*2048 + n] = (fin + 0.25f * t) * 3.14159265358979f;
}

extern "C" void kernel_launch(void* const* d_in, const int* in_sizes, int n_in,
                              void* d_out, int out_size, void* d_ws, size_t ws_size,
                              hipStream_t stream) {
  const float* channel = (const float*)d_in[0];
  const float* We1 = (const float*)d_in[1];
  const float* be1 = (const float*)d_in[2];
  const float* We  = (const float*)d_in[3];
  const float* be  = (const float*)d_in[4];
  const float* Wo1 = (const float*)d_in[5];
  const float* bo1 = (const float*)d_in[6];
  const float* Wo  = (const float*)d_in[7];
  const float* bo  = (const float*)d_in[8];
  const float* W8  = (const float*)d_in[9];
  const float* b8  = (const float*)d_in[10];
  float* out  = (float*)d_out;
  float* part = (float*)d_ws;                       // 2*64*64 floats = 32768 B (cumulative)
  int*   gcnt = (int*)((char*)d_ws + 32768);        // 64 ints

  // stream-ordered zeroing of cumulative rows + counters (graph-capturable)
  hipMemsetAsync(d_ws, 0, 32768 + 64 * sizeof(int), stream);

  void* args[] = { (void*)&channel, (void*)&We1, (void*)&be1, (void*)&We, (void*)&be,
                   (void*)&Wo1, (void*)&bo1, (void*)&Wo, (void*)&bo,
                   (void*)&W8, (void*)&b8, (void*)&out, (void*)&part, (void*)&gcnt };
  hipLaunchCooperativeKernel((void*)risnet_kernel, dim3(GRID), dim3(TPB), args, 0, stream);
}

// Round 23
// 117.771 us; speedup vs baseline: 3.4521x; 1.0116x over previous
//
#include <hip/hip_runtime.h>
#include <hip/hip_cooperative_groups.h>

#define TPB 1024
#define GRID 256   // coop capacity on this stack is <=256 blocks (r2/r7). Never exceed.

// r22 post-mortem: 119us, busy 57 / stall 57. Critical path still carries the
// opp-HI CONV between barrier1 and publish (~1.5us/layer). r23 (reorder only):
// pre-wait phase computes ego-HI + opp-HI accumulators (same 32-VGPR acc
// footprint); post-barrier1 = bias+relu+bfly only -> publish ~1.5us earlier;
// ego-LO + opp-LO convs (bias-init) move into the publish shadow.

typedef float f2 __attribute__((ext_vector_type(2)));
static __device__ __forceinline__ f2 spl(float s) { f2 r; r.x = s; r.y = s; return r; }

__global__ void risnet_kernel(
    const float* __restrict__ channel,
    const float* __restrict__ We1, const float* __restrict__ be1,
    const float* __restrict__ We,  const float* __restrict__ be,
    const float* __restrict__ Wo1, const float* __restrict__ bo1,
    const float* __restrict__ Wo,  const float* __restrict__ bo,
    const float* __restrict__ W8,  const float* __restrict__ b8,
    float* __restrict__ out, float* __restrict__ part, int* __restrict__ gcnt)
{
  const int tid   = threadIdx.x;
  const int lane  = tid & 63;
  const int wv    = tid >> 6;                 // 0..15
  const int p     = tid & 1;                  // user-half: owns users 2p, 2p+1
  const int B     = blockIdx.x;
  const int b     = (B & 7) * 8 + ((B >> 3) & 7);  // same B%8 (XCD) per b-group (perf)
  const int chunk = B >> 6;                   // 0..3
  const int n     = (chunk << 9) | (tid >> 1);// 0..2047

  __shared__ __align__(16) float biasE[2][16][4];  // [L&1][h][u] parity dbuf
  __shared__ __align__(16) float biasO[2][16][4];
  __shared__ float red[64][64];                 // [row=wv*4+grp][conv*32+j*4+u]
  __shared__ float gv[64];                      // per-b mean deltas (wave15 only)
  __shared__ float fin;
  __shared__ int   lcnt;                        // cumulative per-wave publish count

  if (tid == 0) lcnt = 0;

  // per-thread channel slice, packed over the user pair: ch2[f] = {u=2p, u=2p+1}
  f2 ch2[4];
#pragma unroll
  for (int f = 0; f < 4; ++f) {
    ch2[f].x = channel[((b*4 + 2*p + 0)*4 + f)*2048 + n];
    ch2[f].y = channel[((b*4 + 2*p + 1)*4 + f)*2048 + n];
  }
  __syncthreads();   // lcnt init visible before any WAVE_DONE

  f2 el2[8], ol2[8];
  float cum0 = 0.f, cum1 = 0.f;   // wave15: cumulative part-row values per parity
  int   pubt = 16;                // wave0: LDS-counter target for next publish

#define BFLY3(a0, a1) { \
  a0 += __shfl_xor(a0, 2, 64);  a1 += __shfl_xor(a1, 2, 64);  \
  a0 += __shfl_xor(a0, 4, 64);  a1 += __shfl_xor(a1, 4, 64);  \
  a0 += __shfl_xor(a0, 8, 64);  a1 += __shfl_xor(a1, 8, 64); }

#define RED_W(base_col, a0, a1) \
  if ((lane & 15) < 2) { \
    red[(wv<<2)|(lane>>4)][(base_col) + 2*(lane&1) + 0] = a0; \
    red[(wv<<2)|(lane>>4)][(base_col) + 2*(lane&1) + 1] = a1; }

  // this wave's red[] rows for the current epoch are complete
#define WAVE_DONE() { \
  asm volatile("s_waitcnt lgkmcnt(0)" ::: "memory"); \
  if (lane == 0) \
    __hip_atomic_fetch_add(&lcnt, 1, __ATOMIC_RELAXED, __HIP_MEMORY_SCOPE_WORKGROUP); }

  // wave0: poll LDS counter to epoch target, column-sum red, atomicAdd into
  // the CUMULATIVE parity row, drain, bump group counter. No block barrier.
#define PUBLISH_W0(par) \
  if (wv == 0) { \
    for (;;) { \
      int c = __hip_atomic_load(&lcnt, __ATOMIC_RELAXED, __HIP_MEMORY_SCOPE_WORKGROUP); \
      if (c >= pubt) break; \
      __builtin_amdgcn_s_sleep(0); \
    } \
    asm volatile("" ::: "memory"); \
    float s0 = 0.f, s1 = 0.f, s2 = 0.f, s3 = 0.f; \
    _Pragma("unroll") for (int r = 0; r < 64; r += 4) { \
      s0 += red[r+0][lane]; s1 += red[r+1][lane]; \
      s2 += red[r+2][lane]; s3 += red[r+3][lane]; \
    } \
    unsafeAtomicAdd(&part[((par)*64 + b)*64 + lane], (s0+s1)+(s2+s3)); \
    asm volatile("s_waitcnt vmcnt(0)" ::: "memory"); \
    if (lane == 0) \
      __hip_atomic_fetch_add(&gcnt[b], 1, __ATOMIC_RELAXED, __HIP_MEMORY_SCOPE_AGENT); \
  } \
  pubt += 16;

  // single-address relaxed spin on the group counter
#define SPIN_CNT(tgt) { \
  for (;;) { \
    int c = __hip_atomic_load(&gcnt[b], __ATOMIC_RELAXED, __HIP_MEMORY_SCOPE_AGENT); \
    if (c >= (tgt)) break; \
    __builtin_amdgcn_s_sleep(1); \
  } \
  asm volatile("" ::: "memory"); }

  // packed 20-col dot product (ch 0..3, el 4..11, ol 20..27), BINIT = bias or 0
#define DOT20B(ACC, W0, W1, W2, W5, W6, BINIT) { \
  f2 v = (BINIT); \
  v = spl(W0.x)*ch2[0] + v; v = spl(W0.y)*ch2[1] + v; \
  v = spl(W0.z)*ch2[2] + v; v = spl(W0.w)*ch2[3] + v; \
  v = spl(W1.x)*el2[0] + v; v = spl(W1.y)*el2[1] + v; \
  v = spl(W1.z)*el2[2] + v; v = spl(W1.w)*el2[3] + v; \
  v = spl(W2.x)*el2[4] + v; v = spl(W2.y)*el2[5] + v; \
  v = spl(W2.z)*el2[6] + v; v = spl(W2.w)*el2[7] + v; \
  v = spl(W5.x)*ol2[0] + v; v = spl(W5.y)*ol2[1] + v; \
  v = spl(W5.z)*ol2[2] + v; v = spl(W5.w)*ol2[3] + v; \
  v = spl(W6.x)*ol2[4] + v; v = spl(W6.y)*ol2[5] + v; \
  v = spl(W6.z)*ol2[6] + v; v = spl(W6.w)*ol2[7] + v; \
  ACC = v; }

  // ---------------- layer 0 (Cin = 4, feats = ch) ----------------
  {
    f2 opl2[8];
#pragma unroll
    for (int h = 0; h < 16; ++h) {
      const float4 w = *(const float4*)(We1 + h*4);
      f2 a = spl(be1[h]);
      a = spl(w.x)*ch2[0] + a; a = spl(w.y)*ch2[1] + a;
      a = spl(w.z)*ch2[2] + a; a = spl(w.w)*ch2[3] + a;
      a.x = fmaxf(a.x, 0.f); a.y = fmaxf(a.y, 0.f);
      if (h < 8) el2[h] = a;
      else { float a0 = a.x, a1 = a.y; BFLY3(a0, a1); RED_W((h-8)*4, a0, a1); }
    }
#pragma unroll
    for (int h = 0; h < 16; ++h) {
      const float4 w = *(const float4*)(Wo1 + h*4);
      f2 a = spl(bo1[h]);
      a = spl(w.x)*ch2[0] + a; a = spl(w.y)*ch2[1] + a;
      a = spl(w.z)*ch2[2] + a; a = spl(w.w)*ch2[3] + a;
      a.x = fmaxf(a.x, 0.f); a.y = fmaxf(a.y, 0.f);
      if (h < 8) opl2[h] = a;
      else { float a0 = a.x, a1 = a.y; BFLY3(a0, a1); RED_W(32 + (h-8)*4, a0, a1); }
    }
    WAVE_DONE()
    PUBLISH_W0(0)
#pragma unroll
    for (int j = 0; j < 8; ++j) {
      const float s2 = opl2[j].x + opl2[j].y;
      const float s4 = s2 + __shfl_xor(s2, 1, 64);
      ol2[j] = (spl(s4) - opl2[j]) * spl(1.f/3.f);
    }
  }

  // ---------------- layers 1..6 (Cin = 36) ----------------
  for (int L = 1; L < 7; ++L) {
    const float* __restrict__ wEl = We + (L-1)*576;   // wave-uniform -> s_loads
    const float* __restrict__ wOl = Wo + (L-1)*576;
    const int pr = (L-1) & 1;      // parity row holding stats(L-1) cumulative
    const int pw = L & 1;          // parity row this layer publishes into
    const int bb = L & 1;          // bias parity buffer

    // --- phase 1: HI accumulators for BOTH convs, no bias (32 VGPR) ---
    f2 accHiE[8], accHiO[8];
#pragma unroll
    for (int h = 8; h < 16; ++h) {
      const float4* wr = (const float4*)(wEl + h*36);
      const float4 w0 = wr[0], w1 = wr[1], w2 = wr[2], w5 = wr[5], w6 = wr[6];
      DOT20B(accHiE[h-8], w0, w1, w2, w5, w6, spl(0.f))
    }
#pragma unroll
    for (int h = 8; h < 16; ++h) {
      const float4* wr = (const float4*)(wOl + h*36);
      const float4 w0 = wr[0], w1 = wr[1], w2 = wr[2], w5 = wr[5], w6 = wr[6];
      DOT20B(accHiO[h-8], w0, w1, w2, w5, w6, spl(0.f))
    }

    // --- wave15: spin on group counter, read ONE cumulative row, delta, fold ---
    if (wv == 15) {
      SPIN_CNT(4*L)
      float R = __hip_atomic_load(&part[(pr*64 + b)*64 + lane],
                                  __ATOMIC_RELAXED, __HIP_MEMORY_SCOPE_AGENT);
      float prev = pr ? cum1 : cum0;
      float d = R - prev;
      if (pr) cum1 = R; else cum0 = R;
      gv[lane] = d * (1.f/2048.f);
      // same-wave LDS RAW (r11-verified): lane owns (u,h), folds both convs
      const int u = lane & 3;
      const int h = lane >> 2;
      float bE = be[(L-1)*16 + h];
      float bO = bo[(L-1)*16 + h];
#pragma unroll
      for (int j = 0; j < 8; ++j) {
        const float eg = gv[j*4 + u];
        const float so = gv[32+j*4+0] + gv[32+j*4+1] + gv[32+j*4+2] + gv[32+j*4+3];
        const float og = (so - gv[32 + j*4 + u]) * (1.f/3.f);
        bE += wEl[h*36 + 12 + j] * eg + wEl[h*36 + 28 + j] * og;
        bO += wOl[h*36 + 12 + j] * eg + wOl[h*36 + 28 + j] * og;
      }
      biasE[bb][h][u] = bE;
      biasO[bb][h][u] = bO;
    }
    __syncthreads();   // the ONLY block barrier this layer: biases ready

    // --- hi finish: bias + relu + bfly only (NO conv on the publish path) ---
#pragma unroll
    for (int h = 8; h < 16; ++h) {
      f2 a = accHiE[h-8] + *(const f2*)&biasE[bb][h][2*p];
      float a0 = fmaxf(a.x, 0.f), a1 = fmaxf(a.y, 0.f);
      BFLY3(a0, a1); RED_W((h-8)*4, a0, a1);
    }
#pragma unroll
    for (int h = 8; h < 16; ++h) {
      f2 a = accHiO[h-8] + *(const f2*)&biasO[bb][h][2*p];
      float a0 = fmaxf(a.x, 0.f), a1 = fmaxf(a.y, 0.f);
      BFLY3(a0, a1); RED_W(32 + (h-8)*4, a0, a1);
    }
    WAVE_DONE()
    PUBLISH_W0(pw)   // wave0 publishes; other waves fall through to lo halves

    // --- lo convs in the publish shadow (bias-init, biases known) ---
    f2 eln2[8];
#pragma unroll
    for (int h = 0; h < 8; ++h) {
      const float4* wr = (const float4*)(wEl + h*36);
      const float4 w0 = wr[0], w1 = wr[1], w2 = wr[2], w5 = wr[5], w6 = wr[6];
      f2 a;
      DOT20B(a, w0, w1, w2, w5, w6, *(const f2*)&biasE[bb][h][2*p])
      a.x = fmaxf(a.x, 0.f); a.y = fmaxf(a.y, 0.f);
      eln2[h] = a;
    }
    f2 opl2[8];
#pragma unroll
    for (int h = 0; h < 8; ++h) {
      const float4* wr = (const float4*)(wOl + h*36);
      const float4 w0 = wr[0], w1 = wr[1], w2 = wr[2], w5 = wr[5], w6 = wr[6];
      f2 a;
      DOT20B(a, w0, w1, w2, w5, w6, *(const f2*)&biasO[bb][h][2*p])
      a.x = fmaxf(a.x, 0.f); a.y = fmaxf(a.y, 0.f);
      opl2[h] = a;
    }
#pragma unroll
    for (int j = 0; j < 8; ++j) {
      const float s2 = opl2[j].x + opl2[j].y;
      const float s4 = s2 + __shfl_xor(s2, 1, 64);
      ol2[j] = (spl(s4) - opl2[j]) * spl(1.f/3.f);
      el2[j] = eln2[j];
    }
  }

  // ---------------- final 1x1 conv + mean over users ----------------
  if (wv == 15) {   // layer 6 published parity 0; 7 publishes x 4 blocks = 28
    SPIN_CNT(28)
    float R = __hip_atomic_load(&part[(0*64 + b)*64 + lane],
                                __ATOMIC_RELAXED, __HIP_MEMORY_SCOPE_AGENT);
    gv[lane] = (R - cum0) * (1.f/2048.f);
    if (lane == 0) {
      float sf = b8[0];
#pragma unroll
      for (int j = 0; j < 8; ++j) {
        const float so = gv[32+j*4+0] + gv[32+j*4+1] + gv[32+j*4+2] + gv[32+j*4+3];
#pragma unroll
        for (int u = 0; u < 4; ++u) {
          const float eg = gv[j*4 + u];
          const float og = (so - gv[32 + j*4 + u]) * (1.f/3.f);
          sf += 0.25f * (W8[12 + j] * eg + W8[28 + j] * og);
        }
      }
      fin = sf;
    }
  }
  __syncthreads();
  f2 v = spl(0.f);
#pragma unroll
  for (int c = 0; c < 4; ++c) v = spl(W8[c]) * ch2[c] + v;
#pragma unroll
  for (int j = 0; j < 8; ++j) {
    v = spl(W8[4 + j]) * el2[j] + v;
    v = spl(W8[20 + j]) * ol2[j] + v;
  }
  float t = v.x + v.y;
  t += __shfl_xor(t, 1, 64);   // sum over all 4 users
  if (p == 0)
    out[b*2048 + n] = (fin + 0.25f * t) * 3.14159265358979f;
}

extern "C" void kernel_launch(void* const* d_in, const int* in_sizes, int n_in,
                              void* d_out, int out_size, void* d_ws, size_t ws_size,
                              hipStream_t stream) {
  const float* channel = (const float*)d_in[0];
  const float* We1 = (const float*)d_in[1];
  const float* be1 = (const float*)d_in[2];
  const float* We  = (const float*)d_in[3];
  const float* be  = (const float*)d_in[4];
  const float* Wo1 = (const float*)d_in[5];
  const float* bo1 = (const float*)d_in[6];
  const float* Wo  = (const float*)d_in[7];
  const float* bo  = (const float*)d_in[8];
  const float* W8  = (const float*)d_in[9];
  const float* b8  = (const float*)d_in[10];
  float* out  = (float*)d_out;
  float* part = (float*)d_ws;                       // 2*64*64 floats = 32768 B (cumulative)
  int*   gcnt = (int*)((char*)d_ws + 32768);        // 64 ints

  // stream-ordered zeroing of cumulative rows + counters (graph-capturable)
  hipMemsetAsync(d_ws, 0, 32768 + 64 * sizeof(int), stream);

  void* args[] = { (void*)&channel, (void*)&We1, (void*)&be1, (void*)&We, (void*)&be,
                   (void*)&Wo1, (void*)&bo1, (void*)&Wo, (void*)&bo,
                   (void*)&W8, (void*)&b8, (void*)&out, (void*)&part, (void*)&gcnt };
  hipLaunchCooperativeKernel((void*)risnet_kernel, dim3(GRID), dim3(TPB), args, 0, stream);
}